// Round 11
// baseline (225.966 us; speedup 1.0000x reference)
//
#include <hip/hip_runtime.h>
#include <hip/hip_bf16.h>

#define NEG_SLOPE 0.2f
#define BSHIFT 8                 // 256 dsts per bucket
#define BSIZE  (1 << BSHIFT)
#define CAP    9216              // pairs capacity per bucket (mean 8192, +11 sigma)
#define NBMAX  400               // max buckets (n<=102400)
#define SRC_MASK 0x1FFFF         // 17 bits for src id (n < 131072)

typedef float v2f __attribute__((ext_vector_type(2)));

__device__ __forceinline__ float lrelu(float x) { return fmaxf(x, NEG_SLOPE * x); }
__device__ __forceinline__ float bf2f(unsigned short u) {
    return __uint_as_float((unsigned)u << 16);
}
__device__ __forceinline__ unsigned short f2bf(float f) {
    unsigned u = __float_as_uint(f);
    return (unsigned short)((u + 0x7fffu + ((u >> 16) & 1u)) >> 16);  // RNE
}

// Pass 1: h = A @ W as a classic LDS-tiled register GEMM.  (round-5 version)
__global__ __launch_bounds__(256, 4) void k_gemm(
    const float* __restrict__ A, const float* __restrict__ W,
    const float* __restrict__ att,
    unsigned short* __restrict__ h16, float* __restrict__ s_i, float* __restrict__ s_j, int n)
{
    __shared__ float At[64 * 68];   // At[k*68 + r] = A[row0+r][k]
    __shared__ float Wl[64 * 68];   // Wl[k*68 + c] = W[k][c]
    const int tid  = threadIdx.x;
    const int lane = tid & 63;
    const int tx = tid & 15, ty = tid >> 4;
    const int r0 = ty * 4, c0 = tx * 4;
    const long row0 = (long)blockIdx.x * 64;

    {
        int r = tid & 63;
        int kb = (tid >> 6) * 4;
        long gr = row0 + r; if (gr >= n) gr = n - 1;
        const float4* Ar = (const float4*)(A + gr * 64);
#pragma unroll
        for (int p = 0; p < 4; ++p) {
            int k0 = p * 16 + kb;
            float4 a = Ar[k0 >> 2];
            At[(k0 + 0) * 68 + r] = a.x;
            At[(k0 + 1) * 68 + r] = a.y;
            At[(k0 + 2) * 68 + r] = a.z;
            At[(k0 + 3) * 68 + r] = a.w;
        }
        int c = (tid & 15) * 4;
        int rr = tid >> 4;
#pragma unroll
        for (int p = 0; p < 4; ++p) {
            int k = rr + p * 16;
            *(float4*)&Wl[k * 68 + c] = *(const float4*)(W + k * 64 + c);
        }
    }
    __syncthreads();

    float acc[4][4] = {};
#pragma unroll 4
    for (int k = 0; k < 64; ++k) {
        float4 a = *(const float4*)&At[k * 68 + r0];
        float4 w = *(const float4*)&Wl[k * 68 + c0];
        acc[0][0] = fmaf(a.x, w.x, acc[0][0]);
        acc[0][1] = fmaf(a.x, w.y, acc[0][1]);
        acc[0][2] = fmaf(a.x, w.z, acc[0][2]);
        acc[0][3] = fmaf(a.x, w.w, acc[0][3]);
        acc[1][0] = fmaf(a.y, w.x, acc[1][0]);
        acc[1][1] = fmaf(a.y, w.y, acc[1][1]);
        acc[1][2] = fmaf(a.y, w.z, acc[1][2]);
        acc[1][3] = fmaf(a.y, w.w, acc[1][3]);
        acc[2][0] = fmaf(a.z, w.x, acc[2][0]);
        acc[2][1] = fmaf(a.z, w.y, acc[2][1]);
        acc[2][2] = fmaf(a.z, w.z, acc[2][2]);
        acc[2][3] = fmaf(a.z, w.w, acc[2][3]);
        acc[3][0] = fmaf(a.w, w.x, acc[3][0]);
        acc[3][1] = fmaf(a.w, w.y, acc[3][1]);
        acc[3][2] = fmaf(a.w, w.z, acc[3][2]);
        acc[3][3] = fmaf(a.w, w.w, acc[3][3]);
    }

    const int rowlim = (int)(((long)n - row0) < 64 ? (n - row0) : 64);

#pragma unroll
    for (int i = 0; i < 4; ++i) {
        int r = r0 + i;
        if (r < rowlim) {
            uint2 uv;
            uv.x = (unsigned)f2bf(acc[i][0]) | ((unsigned)f2bf(acc[i][1]) << 16);
            uv.y = (unsigned)f2bf(acc[i][2]) | ((unsigned)f2bf(acc[i][3]) << 16);
            *(uint2*)(h16 + (row0 + r) * 64 + c0) = uv;
        }
    }

    float4 avi = *(const float4*)(att + c0);
    float4 avj = *(const float4*)(att + 64 + c0);
#pragma unroll
    for (int i = 0; i < 4; ++i) {
        float pi = acc[i][0] * avi.x;
        pi = fmaf(acc[i][1], avi.y, pi);
        pi = fmaf(acc[i][2], avi.z, pi);
        pi = fmaf(acc[i][3], avi.w, pi);
        float pj = acc[i][0] * avj.x;
        pj = fmaf(acc[i][1], avj.y, pj);
        pj = fmaf(acc[i][2], avj.z, pj);
        pj = fmaf(acc[i][3], avj.w, pj);
#pragma unroll
        for (int o = 1; o <= 8; o <<= 1) {
            pi += __shfl_xor(pi, o, 64);
            pj += __shfl_xor(pj, o, 64);
        }
        int r = r0 + i;
        if ((lane & 15) == 0 && r < rowlim) {
            s_i[row0 + r] = pi;
            s_j[row0 + r] = pj;
        }
    }
}

// Bin step A: 512 thr / 8192 edges, register-staged, LDS-staged coalesced
// flush, wave-shfl scan (round-10 version).
__global__ __launch_bounds__(512) void k_binA(
    const int* __restrict__ edges, int* __restrict__ bcursor,
    unsigned* __restrict__ pairs, int n_edges, int nb)
{
    __shared__ int hist[512];
    __shared__ int st[512];
    __shared__ int cur[512];
    __shared__ int gbase[512];
    __shared__ int wsum[8];
    __shared__ unsigned lp[8192];        // 32 KB
    const int t = threadIdx.x;
    const int w = t >> 6, lane = t & 63;
    const long base = (long)blockIdx.x * 8192;

    int er[16];
#pragma unroll
    for (int k = 0; k < 16; ++k) {
        long e = base + k * 512 + t;
        int d = -1;
        if (e < n_edges) {
            d = edges[e];
            if (d == (int)(e >> 5)) d = -1;   // drop self-loops
        }
        er[k] = d;
    }

    hist[t] = 0;
    __syncthreads();
#pragma unroll
    for (int k = 0; k < 16; ++k)
        if (er[k] >= 0) atomicAdd(&hist[er[k] >> BSHIFT], 1);
    __syncthreads();

    int hv = hist[t];
    int inc = hv;
#pragma unroll
    for (int off = 1; off < 64; off <<= 1) {
        int u = __shfl_up(inc, off, 64);
        if (lane >= off) inc += u;
    }
    if (lane == 63) wsum[w] = inc;
    __syncthreads();
    {
        int wb_ = 0;
        for (int i = 0; i < w; ++i) wb_ += wsum[i];   // wave-uniform, <=7 reads
        int s0 = inc - hv + wb_;                       // exclusive prefix
        st[t] = s0;
        cur[t] = s0;
        gbase[t] = 0;
    }
    if (t < nb && hist[t] > 0) gbase[t] = atomicAdd(&bcursor[t], hist[t]);
    __syncthreads();

#pragma unroll
    for (int k = 0; k < 16; ++k) {
        int d = er[k];
        if (d >= 0) {
            int b = d >> BSHIFT;
            int slot = atomicAdd(&cur[b], 1);
            long e = base + k * 512 + t;
            lp[slot] = ((unsigned)(d & (BSIZE - 1)) << 17) | (unsigned)(e >> 5);
        }
    }
    __syncthreads();

    for (int b = w; b < nb; b += 8) {
        int cnt = hist[b];
        int gb  = gbase[b];
        int cw  = cnt;
        if (gb + cw > CAP) cw = CAP - gb;   // overflow guard (drop excess)
        long gdst = (long)b * CAP + gb;
        int sb = st[b];
        for (int s = lane; s < cw; s += 64)
            pairs[gdst + s] = lp[sb + s];
    }
}

// Bin step B: counting sort per bucket, wave-shfl scan (round-10 version).
__global__ __launch_bounds__(512) void k_binB(
    const int* __restrict__ bcursor, unsigned* __restrict__ pairs,
    int* __restrict__ offs, int* __restrict__ counts, int n)
{
    __shared__ unsigned pl[CAP];         // 36 KB
    __shared__ unsigned srt[CAP];        // 36 KB
    __shared__ int hist[BSIZE];
    __shared__ int cur[BSIZE];
    __shared__ int wsum[4];
    int b = blockIdx.x, t = threadIdx.x;
    const int w = t >> 6, lane = t & 63;
    int cnt = bcursor[b];
    if (cnt > CAP) cnt = CAP;
    long wb = (long)b * CAP;

    for (int s = t; s < cnt; s += 512) pl[s] = pairs[wb + s];
    if (t < BSIZE) hist[t] = 0;
    __syncthreads();
    for (int s = t; s < cnt; s += 512) atomicAdd(&hist[pl[s] >> 17], 1);
    __syncthreads();

    int hv = (t < BSIZE) ? hist[t] : 0;
    int inc = hv;
#pragma unroll
    for (int off = 1; off < 64; off <<= 1) {
        int u = __shfl_up(inc, off, 64);
        if (lane >= off) inc += u;
    }
    if (t < BSIZE && lane == 63) wsum[w] = inc;
    __syncthreads();
    if (t < BSIZE) {
        int wb_ = 0;
        for (int i = 0; i < w; ++i) wb_ += wsum[i];
        int start = inc - hv + wb_;
        int dg = (b << BSHIFT) + t;
        if (dg < n) {
            offs[dg]   = (int)(wb + start);
            counts[dg] = hv;
        }
        cur[t] = start;
    }
    __syncthreads();

    for (int s = t; s < cnt; s += 512) {
        unsigned pk = pl[s];
        int pos = atomicAdd(&cur[pk >> 17], 1);
        srt[pos] = pk & SRC_MASK;
    }
    __syncthreads();

    for (int s = t; s < cnt; s += 512)
        ((int*)pairs)[wb + s] = (int)srt[s];
}

// Gather: wave per dst, 8 groups x 8 lanes. MLP-widened: 32 edges per step
// with FOUR independent dwordx4 row loads in flight (round-10's 2-in-flight
// sustained only ~2.6 TB/s = latency-limited; pk_fma cut proved non-VALU-
// bound). Self-loop hd row + bias issued BEFORE the main loop to hide the
// epilogue's serial latency. Inert-lane tail (w=0 -> row-0 L2 hits).
__global__ __launch_bounds__(256) void k_gather(
    const int* __restrict__ offs, const int* __restrict__ counts,
    const int* __restrict__ srcl, const unsigned short* __restrict__ h16,
    const float* __restrict__ s_i, const float* __restrict__ s_j,
    const float* __restrict__ bias, float* __restrict__ out, int n)
{
    int gw = (blockIdx.x * 256 + threadIdx.x) >> 6;
    int lane = threadIdx.x & 63;
    if (gw >= n) return;
    const int d = gw;
    const int off = offs[d], deg = counts[d];
    const float si = s_i[d];
    const float es = __expf(lrelu(si + s_j[d]));   // self-loop weight

    const int g  = lane >> 3;                      // group: which edge of 8
    const int li = lane & 7;                       // dims [li*8, li*8+8)
    const char* hb = (const char*)h16 + (li << 4); // +16B per lane-in-group

    // issue epilogue loads early (latency hidden under the main loop)
    uint4 hd = *(const uint4*)(hb + (d << 7));
    const float4* pb = (const float4*)(bias + (li << 3));
    float4 b0 = pb[0], b1 = pb[1];

    v2f acc2[4];
#pragma unroll
    for (int i = 0; i < 4; ++i) acc2[i] = (v2f)0.f;
    float denp = 0.f;

    for (int base = 0; base < deg; base += 64) {
        int t = base + lane;
        int cnt = min(64, deg - base);
        int soff = 0; float w = 0.f;
        if (t < deg) {
            int s = srcl[off + t];
            soff = s << 7;                         // byte offset of row s
            w = __expf(lrelu(si + s_j[s]));
        }
        denp += w;
        int j = 0;
        // 32 edges per step: 8 bpermutes + 4 independent dwordx4 loads
        for (; j + 32 <= cnt; j += 32) {
            int i0 = j + g, i1 = j + 8 + g, i2 = j + 16 + g, i3 = j + 24 + g;
            float w0 = __shfl(w, i0, 64);
            int   o0 = __shfl(soff, i0, 64);
            float w1 = __shfl(w, i1, 64);
            int   o1 = __shfl(soff, i1, 64);
            float w2 = __shfl(w, i2, 64);
            int   o2 = __shfl(soff, i2, 64);
            float w3 = __shfl(w, i3, 64);
            int   o3 = __shfl(soff, i3, 64);
            uint4 ha = *(const uint4*)(hb + o0);
            uint4 hc = *(const uint4*)(hb + o1);
            uint4 he = *(const uint4*)(hb + o2);
            uint4 hf = *(const uint4*)(hb + o3);
            v2f w0v = {w0, w0}, w1v = {w1, w1}, w2v = {w2, w2}, w3v = {w3, w3};
            v2f p;
            p = (v2f){__uint_as_float(ha.x << 16), __uint_as_float(ha.x & 0xffff0000u)};
            acc2[0] += p * w0v;
            p = (v2f){__uint_as_float(ha.y << 16), __uint_as_float(ha.y & 0xffff0000u)};
            acc2[1] += p * w0v;
            p = (v2f){__uint_as_float(ha.z << 16), __uint_as_float(ha.z & 0xffff0000u)};
            acc2[2] += p * w0v;
            p = (v2f){__uint_as_float(ha.w << 16), __uint_as_float(ha.w & 0xffff0000u)};
            acc2[3] += p * w0v;
            p = (v2f){__uint_as_float(hc.x << 16), __uint_as_float(hc.x & 0xffff0000u)};
            acc2[0] += p * w1v;
            p = (v2f){__uint_as_float(hc.y << 16), __uint_as_float(hc.y & 0xffff0000u)};
            acc2[1] += p * w1v;
            p = (v2f){__uint_as_float(hc.z << 16), __uint_as_float(hc.z & 0xffff0000u)};
            acc2[2] += p * w1v;
            p = (v2f){__uint_as_float(hc.w << 16), __uint_as_float(hc.w & 0xffff0000u)};
            acc2[3] += p * w1v;
            p = (v2f){__uint_as_float(he.x << 16), __uint_as_float(he.x & 0xffff0000u)};
            acc2[0] += p * w2v;
            p = (v2f){__uint_as_float(he.y << 16), __uint_as_float(he.y & 0xffff0000u)};
            acc2[1] += p * w2v;
            p = (v2f){__uint_as_float(he.z << 16), __uint_as_float(he.z & 0xffff0000u)};
            acc2[2] += p * w2v;
            p = (v2f){__uint_as_float(he.w << 16), __uint_as_float(he.w & 0xffff0000u)};
            acc2[3] += p * w2v;
            p = (v2f){__uint_as_float(hf.x << 16), __uint_as_float(hf.x & 0xffff0000u)};
            acc2[0] += p * w3v;
            p = (v2f){__uint_as_float(hf.y << 16), __uint_as_float(hf.y & 0xffff0000u)};
            acc2[1] += p * w3v;
            p = (v2f){__uint_as_float(hf.z << 16), __uint_as_float(hf.z & 0xffff0000u)};
            acc2[2] += p * w3v;
            p = (v2f){__uint_as_float(hf.w << 16), __uint_as_float(hf.w & 0xffff0000u)};
            acc2[3] += p * w3v;
        }
        // remainder: 16 edges per step, 2 loads (inert beyond cnt)
        for (; j < cnt; j += 16) {
            int i0 = j + g, i1 = j + 8 + g;
            float w0 = __shfl(w, i0, 64);
            int   o0 = __shfl(soff, i0, 64);
            float w1 = __shfl(w, i1, 64);
            int   o1 = __shfl(soff, i1, 64);
            uint4 ha = *(const uint4*)(hb + o0);
            uint4 hc = *(const uint4*)(hb + o1);
            v2f w0v = {w0, w0}, w1v = {w1, w1};
            v2f p;
            p = (v2f){__uint_as_float(ha.x << 16), __uint_as_float(ha.x & 0xffff0000u)};
            acc2[0] += p * w0v;
            p = (v2f){__uint_as_float(ha.y << 16), __uint_as_float(ha.y & 0xffff0000u)};
            acc2[1] += p * w0v;
            p = (v2f){__uint_as_float(ha.z << 16), __uint_as_float(ha.z & 0xffff0000u)};
            acc2[2] += p * w0v;
            p = (v2f){__uint_as_float(ha.w << 16), __uint_as_float(ha.w & 0xffff0000u)};
            acc2[3] += p * w0v;
            p = (v2f){__uint_as_float(hc.x << 16), __uint_as_float(hc.x & 0xffff0000u)};
            acc2[0] += p * w1v;
            p = (v2f){__uint_as_float(hc.y << 16), __uint_as_float(hc.y & 0xffff0000u)};
            acc2[1] += p * w1v;
            p = (v2f){__uint_as_float(hc.z << 16), __uint_as_float(hc.z & 0xffff0000u)};
            acc2[2] += p * w1v;
            p = (v2f){__uint_as_float(hc.w << 16), __uint_as_float(hc.w & 0xffff0000u)};
            acc2[3] += p * w1v;
        }
    }

    float acc[8];
    acc[0] = acc2[0].x; acc[1] = acc2[0].y;
    acc[2] = acc2[1].x; acc[3] = acc2[1].y;
    acc[4] = acc2[2].x; acc[5] = acc2[2].y;
    acc[6] = acc2[3].x; acc[7] = acc2[3].y;

    // reduce group partials: groups live in lane bits 3..5 -> xor 8,16,32
#pragma unroll
    for (int o = 8; o <= 32; o <<= 1) {
#pragma unroll
        for (int i = 0; i < 8; ++i)
            acc[i] += __shfl_xor(acc[i], o, 64);
    }
    // den partials over all 64 lanes
#pragma unroll
    for (int o = 32; o; o >>= 1) denp += __shfl_xor(denp, o, 64);

    // self loop + epilogue (hd/bias already in registers)
    float den = denp + es + 1e-16f;
    float rden = 1.f / den;

    float v[8];
    v[0] = fmaf(__uint_as_float(hd.x << 16),         es, acc[0]) * rden + b0.x;
    v[1] = fmaf(__uint_as_float(hd.x & 0xffff0000u), es, acc[1]) * rden + b0.y;
    v[2] = fmaf(__uint_as_float(hd.y << 16),         es, acc[2]) * rden + b0.z;
    v[3] = fmaf(__uint_as_float(hd.y & 0xffff0000u), es, acc[3]) * rden + b0.w;
    v[4] = fmaf(__uint_as_float(hd.z << 16),         es, acc[4]) * rden + b1.x;
    v[5] = fmaf(__uint_as_float(hd.z & 0xffff0000u), es, acc[5]) * rden + b1.y;
    v[6] = fmaf(__uint_as_float(hd.w << 16),         es, acc[6]) * rden + b1.z;
    v[7] = fmaf(__uint_as_float(hd.w & 0xffff0000u), es, acc[7]) * rden + b1.w;

    float sq = 0.f;
#pragma unroll
    for (int i = 0; i < 8; ++i) sq = fmaf(v[i], v[i], sq);
#pragma unroll
    for (int o = 1; o <= 4; o <<= 1) sq += __shfl_xor(sq, o, 64);
    float rn = 1.f / fmaxf(sqrtf(sq), 1e-12f);

    if (g < 2) {   // groups 0/1 write dims [li*8+4g, li*8+4g+4) once each
        float4 ov;
        if (g == 0) ov = make_float4(v[0] * rn, v[1] * rn, v[2] * rn, v[3] * rn);
        else        ov = make_float4(v[4] * rn, v[5] * rn, v[6] * rn, v[7] * rn);
        *(float4*)(out + ((long)d << 6) + (li << 3) + (g << 2)) = ov;
    }
}

extern "C" void kernel_launch(void* const* d_in, const int* in_sizes, int n_in,
                              void* d_out, int out_size, void* d_ws, size_t ws_size,
                              hipStream_t stream)
{
    const float* A    = (const float*)d_in[0]; // all_embed (n,64) f32
    const float* W    = (const float*)d_in[1]; // (64,64) f32
    const float* att  = (const float*)d_in[2]; // (128,) f32
    const float* bias = (const float*)d_in[3]; // (64,) f32
    const int* edges  = (const int*)d_in[7];   // (n,32) int32

    int n = in_sizes[0] / 64;          // 100000
    int n_edges = in_sizes[7];         // n * 32
    int nb = (n + BSIZE - 1) >> BSHIFT; // 391 buckets

    // workspace layout
    unsigned short* h16 = (unsigned short*)d_ws;    // n*64 bf16
    float* s_i      = (float*)(h16 + (long)n * 64); // n
    float* s_j      = s_i + n;                      // n
    int* offs       = (int*)(s_j + n);              // n
    int* counts     = offs + n;                     // n
    int* bcursor    = counts + n;                   // 512
    unsigned* pairs = (unsigned*)(bcursor + 512);   // nb*CAP (aliased as srcl after binB)

    (void)hipMemsetAsync(bcursor, 0, 512 * sizeof(int), stream);

    int blocks_rows = (n + 63) / 64;                // 64 rows per block
    k_gemm<<<blocks_rows, 256, 0, stream>>>(A, W, att, h16, s_i, s_j, n);

    int blocks_binA = (n_edges + 8191) / 8192;      // 391
    k_binA<<<blocks_binA, 512, 0, stream>>>(edges, bcursor, pairs, n_edges, nb);

    k_binB<<<nb, 512, 0, stream>>>(bcursor, pairs, offs, counts, n);

    int blocks_waves = ((long)n * 64 + 255) / 256;  // wave per dst
    k_gather<<<blocks_waves, 256, 0, stream>>>(offs, counts, (const int*)pairs, h16,
                                               s_i, s_j, bias, (float*)d_out, n);
}

// Round 12
// 197.774 us; speedup vs baseline: 1.1426x; 1.1426x over previous
//
#include <hip/hip_runtime.h>
#include <hip/hip_bf16.h>

#define NEG_SLOPE 0.2f
#define BSHIFT 8                 // 256 dsts per bucket
#define BSIZE  (1 << BSHIFT)
#define CAP    9216              // pairs capacity per bucket (mean 8192, +11 sigma)
#define NBMAX  400               // max buckets (n<=102400)
#define SRC_MASK 0x1FFFF         // 17 bits for src id (n < 131072)

typedef float v2f __attribute__((ext_vector_type(2)));

__device__ __forceinline__ float lrelu(float x) { return fmaxf(x, NEG_SLOPE * x); }
__device__ __forceinline__ float bf2f(unsigned short u) {
    return __uint_as_float((unsigned)u << 16);
}
__device__ __forceinline__ unsigned short f2bf(float f) {
    unsigned u = __float_as_uint(f);
    return (unsigned short)((u + 0x7fffu + ((u >> 16) & 1u)) >> 16);  // RNE
}

// Fused front: blocks [0, nba) run binA (edge bucketing); blocks [nba, ...)
// run the 64x64 LDS-tiled GEMM. The two are data-independent; co-residency
// lets gemm's fma streams fill binA's DS-atomic/barrier stalls. binA blocks
// come FIRST so they are resident from t=0. Shared mem is a union (40960 B
// -> 4 blocks/CU); binA's wsum aliases gbase[504..511] (buckets < 400).
__global__ __launch_bounds__(512, 8) void k_front(
    const float* __restrict__ A, const float* __restrict__ W,
    const float* __restrict__ att,
    unsigned short* __restrict__ h16, float* __restrict__ s_i, float* __restrict__ s_j, int n,
    const int* __restrict__ edges, int* __restrict__ bcursor,
    unsigned* __restrict__ pairs, int n_edges, int nb, int nba)
{
    __shared__ union {
        struct { float At[64 * 68]; float Wl[64 * 68]; } g;              // 34816 B
        struct { int hist[512]; int st[512]; int cur[512];
                 int gbase[512]; unsigned lp[8192]; } b;                 // 40960 B
    } sh;
    const int t = threadIdx.x;

    if ((int)blockIdx.x < nba) {
        // ---------------- binA body (round-10 logic) ----------------
        int* hist = sh.b.hist; int* st = sh.b.st; int* cur = sh.b.cur;
        int* gbase = sh.b.gbase; unsigned* lp = sh.b.lp;
        int* wsum = gbase + 504;         // alias: gbase[504..511] unused (nb<=400)
        const int w = t >> 6, lane = t & 63;
        const long base = (long)blockIdx.x * 8192;

        int er[16];
#pragma unroll
        for (int k = 0; k < 16; ++k) {
            long e = base + k * 512 + t;
            int d = -1;
            if (e < n_edges) {
                d = edges[e];
                if (d == (int)(e >> 5)) d = -1;   // drop self-loops
            }
            er[k] = d;
        }

        hist[t] = 0;
        __syncthreads();
#pragma unroll
        for (int k = 0; k < 16; ++k)
            if (er[k] >= 0) atomicAdd(&hist[er[k] >> BSHIFT], 1);
        __syncthreads();

        int hv = hist[t];
        int inc = hv;
#pragma unroll
        for (int off = 1; off < 64; off <<= 1) {
            int u = __shfl_up(inc, off, 64);
            if (lane >= off) inc += u;
        }
        if (lane == 63) wsum[w] = inc;
        __syncthreads();
        {
            int wb_ = 0;
            for (int i = 0; i < w; ++i) wb_ += wsum[i];   // wave-uniform
            int s0 = inc - hv + wb_;                       // exclusive prefix
            st[t] = s0;
            cur[t] = s0;
            if (t < NBMAX) gbase[t] = 0;                   // guard: keep wsum alias intact
        }
        __syncthreads();                                   // wsum reads done before reserve
        if (t < nb && hist[t] > 0) gbase[t] = atomicAdd(&bcursor[t], hist[t]);
        __syncthreads();

#pragma unroll
        for (int k = 0; k < 16; ++k) {
            int d = er[k];
            if (d >= 0) {
                int b = d >> BSHIFT;
                int slot = atomicAdd(&cur[b], 1);
                long e = base + k * 512 + t;
                lp[slot] = ((unsigned)(d & (BSIZE - 1)) << 17) | (unsigned)(e >> 5);
            }
        }
        __syncthreads();

        for (int b = w; b < nb; b += 8) {
            int cnt = hist[b];
            int gb  = gbase[b];
            int cw  = cnt;
            if (gb + cw > CAP) cw = CAP - gb;   // overflow guard
            long gdst = (long)b * CAP + gb;
            int sb = st[b];
            for (int s = lane; s < cw; s += 64)
                pairs[gdst + s] = lp[sb + s];
        }
    } else {
        // ---------------- gemm body (512-thread variant) ----------------
        float* At = sh.g.At; float* Wl = sh.g.Wl;
        const int lane = t & 63;
        const int tx = t & 15, ty = t >> 4;       // 32 x 16 threads
        const int r0 = ty * 2, c0 = tx * 4;       // 2x4 register tile
        const long row0 = (long)(blockIdx.x - nba) * 64;

        {
            int r = t & 63;
            int kb = (t >> 6) * 4;                // 0,4,...,28
            long gr = row0 + r; if (gr >= n) gr = n - 1;
            const float4* Ar = (const float4*)(A + gr * 64);
#pragma unroll
            for (int p = 0; p < 2; ++p) {
                int k0 = p * 32 + kb;
                float4 a = Ar[k0 >> 2];
                At[(k0 + 0) * 68 + r] = a.x;
                At[(k0 + 1) * 68 + r] = a.y;
                At[(k0 + 2) * 68 + r] = a.z;
                At[(k0 + 3) * 68 + r] = a.w;
            }
            int rr = t >> 4;                      // 0..31
#pragma unroll
            for (int p = 0; p < 2; ++p) {
                int k = rr + p * 32;
                *(float4*)&Wl[k * 68 + c0] = *(const float4*)(W + k * 64 + c0);
            }
        }
        __syncthreads();

        float acc[2][4] = {};
#pragma unroll 4
        for (int k = 0; k < 64; ++k) {
            float2 a = *(const float2*)&At[k * 68 + r0];
            float4 w4 = *(const float4*)&Wl[k * 68 + c0];
            acc[0][0] = fmaf(a.x, w4.x, acc[0][0]);
            acc[0][1] = fmaf(a.x, w4.y, acc[0][1]);
            acc[0][2] = fmaf(a.x, w4.z, acc[0][2]);
            acc[0][3] = fmaf(a.x, w4.w, acc[0][3]);
            acc[1][0] = fmaf(a.y, w4.x, acc[1][0]);
            acc[1][1] = fmaf(a.y, w4.y, acc[1][1]);
            acc[1][2] = fmaf(a.y, w4.z, acc[1][2]);
            acc[1][3] = fmaf(a.y, w4.w, acc[1][3]);
        }

        const int rowlim = (int)(((long)n - row0) < 64 ? (n - row0) : 64);

#pragma unroll
        for (int i = 0; i < 2; ++i) {
            int r = r0 + i;
            if (r < rowlim) {
                uint2 uv;
                uv.x = (unsigned)f2bf(acc[i][0]) | ((unsigned)f2bf(acc[i][1]) << 16);
                uv.y = (unsigned)f2bf(acc[i][2]) | ((unsigned)f2bf(acc[i][3]) << 16);
                *(uint2*)(h16 + (row0 + r) * 64 + c0) = uv;
            }
        }

        float4 avi = *(const float4*)(att + c0);
        float4 avj = *(const float4*)(att + 64 + c0);
#pragma unroll
        for (int i = 0; i < 2; ++i) {
            float pi = acc[i][0] * avi.x;
            pi = fmaf(acc[i][1], avi.y, pi);
            pi = fmaf(acc[i][2], avi.z, pi);
            pi = fmaf(acc[i][3], avi.w, pi);
            float pj = acc[i][0] * avj.x;
            pj = fmaf(acc[i][1], avj.y, pj);
            pj = fmaf(acc[i][2], avj.z, pj);
            pj = fmaf(acc[i][3], avj.w, pj);
#pragma unroll
            for (int o = 1; o <= 8; o <<= 1) {
                pi += __shfl_xor(pi, o, 64);
                pj += __shfl_xor(pj, o, 64);
            }
            int r = r0 + i;
            if ((lane & 15) == 0 && r < rowlim) {
                s_i[row0 + r] = pi;
                s_j[row0 + r] = pj;
            }
        }
    }
}

// Bin step B: counting sort per bucket, wave-shfl scan (round-10 version).
__global__ __launch_bounds__(512) void k_binB(
    const int* __restrict__ bcursor, unsigned* __restrict__ pairs,
    int* __restrict__ offs, int* __restrict__ counts, int n)
{
    __shared__ unsigned pl[CAP];         // 36 KB
    __shared__ unsigned srt[CAP];        // 36 KB
    __shared__ int hist[BSIZE];
    __shared__ int cur[BSIZE];
    __shared__ int wsum[4];
    int b = blockIdx.x, t = threadIdx.x;
    const int w = t >> 6, lane = t & 63;
    int cnt = bcursor[b];
    if (cnt > CAP) cnt = CAP;
    long wb = (long)b * CAP;

    for (int s = t; s < cnt; s += 512) pl[s] = pairs[wb + s];
    if (t < BSIZE) hist[t] = 0;
    __syncthreads();
    for (int s = t; s < cnt; s += 512) atomicAdd(&hist[pl[s] >> 17], 1);
    __syncthreads();

    int hv = (t < BSIZE) ? hist[t] : 0;
    int inc = hv;
#pragma unroll
    for (int off = 1; off < 64; off <<= 1) {
        int u = __shfl_up(inc, off, 64);
        if (lane >= off) inc += u;
    }
    if (t < BSIZE && lane == 63) wsum[w] = inc;
    __syncthreads();
    if (t < BSIZE) {
        int wb_ = 0;
        for (int i = 0; i < w; ++i) wb_ += wsum[i];
        int start = inc - hv + wb_;
        int dg = (b << BSHIFT) + t;
        if (dg < n) {
            offs[dg]   = (int)(wb + start);
            counts[dg] = hv;
        }
        cur[t] = start;
    }
    __syncthreads();

    for (int s = t; s < cnt; s += 512) {
        unsigned pk = pl[s];
        int pos = atomicAdd(&cur[pk >> 17], 1);
        srt[pos] = pk & SRC_MASK;
    }
    __syncthreads();

    for (int s = t; s < cnt; s += 512)
        ((int*)pairs)[wb + s] = (int)srt[s];
}

// Gather: wave per dst, 8 groups x 8 lanes, v2f accumulators (round-10
// version, 65.8us best measured — rounds 10/11 proved it is neither
// VALU-issue- nor per-wave-MLP-bound; leave structure alone).
__global__ __launch_bounds__(256) void k_gather(
    const int* __restrict__ offs, const int* __restrict__ counts,
    const int* __restrict__ srcl, const unsigned short* __restrict__ h16,
    const float* __restrict__ s_i, const float* __restrict__ s_j,
    const float* __restrict__ bias, float* __restrict__ out, int n)
{
    int gw = (blockIdx.x * 256 + threadIdx.x) >> 6;
    int lane = threadIdx.x & 63;
    if (gw >= n) return;
    const int d = gw;
    const int off = offs[d], deg = counts[d];
    const float si = s_i[d];
    const float es = __expf(lrelu(si + s_j[d]));   // self-loop weight

    const int g  = lane >> 3;                      // group: which edge of 8
    const int li = lane & 7;                       // dims [li*8, li*8+8)
    const char* hb = (const char*)h16 + (li << 4); // +16B per lane-in-group

    v2f acc2[4];
#pragma unroll
    for (int i = 0; i < 4; ++i) acc2[i] = (v2f)0.f;
    float denp = 0.f;

    for (int base = 0; base < deg; base += 64) {
        int t = base + lane;
        int cnt = min(64, deg - base);
        int soff = 0; float w = 0.f;
        if (t < deg) {
            int s = srcl[off + t];
            soff = s << 7;                         // byte offset of row s
            w = __expf(lrelu(si + s_j[s]));
        }
        denp += w;
        // 16 edges per iteration: 4 bpermutes + 2 dwordx4 loads + 16 pk_fma
        for (int j = 0; j < cnt; j += 16) {
            int i0 = j + g, i1 = j + 8 + g;
            float w0 = __shfl(w, i0, 64);
            int   o0 = __shfl(soff, i0, 64);
            float w1 = __shfl(w, i1, 64);
            int   o1 = __shfl(soff, i1, 64);
            uint4 ha = *(const uint4*)(hb + o0);
            uint4 hc = *(const uint4*)(hb + o1);
            v2f w0v = {w0, w0};
            v2f w1v = {w1, w1};
            v2f p;
            p = (v2f){__uint_as_float(ha.x << 16), __uint_as_float(ha.x & 0xffff0000u)};
            acc2[0] += p * w0v;
            p = (v2f){__uint_as_float(ha.y << 16), __uint_as_float(ha.y & 0xffff0000u)};
            acc2[1] += p * w0v;
            p = (v2f){__uint_as_float(ha.z << 16), __uint_as_float(ha.z & 0xffff0000u)};
            acc2[2] += p * w0v;
            p = (v2f){__uint_as_float(ha.w << 16), __uint_as_float(ha.w & 0xffff0000u)};
            acc2[3] += p * w0v;
            p = (v2f){__uint_as_float(hc.x << 16), __uint_as_float(hc.x & 0xffff0000u)};
            acc2[0] += p * w1v;
            p = (v2f){__uint_as_float(hc.y << 16), __uint_as_float(hc.y & 0xffff0000u)};
            acc2[1] += p * w1v;
            p = (v2f){__uint_as_float(hc.z << 16), __uint_as_float(hc.z & 0xffff0000u)};
            acc2[2] += p * w1v;
            p = (v2f){__uint_as_float(hc.w << 16), __uint_as_float(hc.w & 0xffff0000u)};
            acc2[3] += p * w1v;
        }
    }

    float acc[8];
    acc[0] = acc2[0].x; acc[1] = acc2[0].y;
    acc[2] = acc2[1].x; acc[3] = acc2[1].y;
    acc[4] = acc2[2].x; acc[5] = acc2[2].y;
    acc[6] = acc2[3].x; acc[7] = acc2[3].y;

    // reduce group partials: groups live in lane bits 3..5 -> xor 8,16,32
#pragma unroll
    for (int o = 8; o <= 32; o <<= 1) {
#pragma unroll
        for (int i = 0; i < 8; ++i)
            acc[i] += __shfl_xor(acc[i], o, 64);
    }
    // den partials over all 64 lanes
#pragma unroll
    for (int o = 32; o; o >>= 1) denp += __shfl_xor(denp, o, 64);

    // self loop + epilogue (all groups hold identical values from here on)
    uint4 hd = *(const uint4*)(hb + (d << 7));
    float den = denp + es + 1e-16f;
    float rden = 1.f / den;
    const float4* pb = (const float4*)(bias + (li << 3));
    float4 b0 = pb[0], b1 = pb[1];

    float v[8];
    v[0] = fmaf(__uint_as_float(hd.x << 16),         es, acc[0]) * rden + b0.x;
    v[1] = fmaf(__uint_as_float(hd.x & 0xffff0000u), es, acc[1]) * rden + b0.y;
    v[2] = fmaf(__uint_as_float(hd.y << 16),         es, acc[2]) * rden + b0.z;
    v[3] = fmaf(__uint_as_float(hd.y & 0xffff0000u), es, acc[3]) * rden + b0.w;
    v[4] = fmaf(__uint_as_float(hd.z << 16),         es, acc[4]) * rden + b1.x;
    v[5] = fmaf(__uint_as_float(hd.z & 0xffff0000u), es, acc[5]) * rden + b1.y;
    v[6] = fmaf(__uint_as_float(hd.w << 16),         es, acc[6]) * rden + b1.z;
    v[7] = fmaf(__uint_as_float(hd.w & 0xffff0000u), es, acc[7]) * rden + b1.w;

    float sq = 0.f;
#pragma unroll
    for (int i = 0; i < 8; ++i) sq = fmaf(v[i], v[i], sq);
#pragma unroll
    for (int o = 1; o <= 4; o <<= 1) sq += __shfl_xor(sq, o, 64);
    float rn = 1.f / fmaxf(sqrtf(sq), 1e-12f);

    if (g < 2) {   // groups 0/1 write dims [li*8+4g, li*8+4g+4) once each
        float4 ov;
        if (g == 0) ov = make_float4(v[0] * rn, v[1] * rn, v[2] * rn, v[3] * rn);
        else        ov = make_float4(v[4] * rn, v[5] * rn, v[6] * rn, v[7] * rn);
        *(float4*)(out + ((long)d << 6) + (li << 3) + (g << 2)) = ov;
    }
}

extern "C" void kernel_launch(void* const* d_in, const int* in_sizes, int n_in,
                              void* d_out, int out_size, void* d_ws, size_t ws_size,
                              hipStream_t stream)
{
    const float* A    = (const float*)d_in[0]; // all_embed (n,64) f32
    const float* W    = (const float*)d_in[1]; // (64,64) f32
    const float* att  = (const float*)d_in[2]; // (128,) f32
    const float* bias = (const float*)d_in[3]; // (64,) f32
    const int* edges  = (const int*)d_in[7];   // (n,32) int32

    int n = in_sizes[0] / 64;          // 100000
    int n_edges = in_sizes[7];         // n * 32
    int nb = (n + BSIZE - 1) >> BSHIFT; // 391 buckets

    // workspace layout
    unsigned short* h16 = (unsigned short*)d_ws;    // n*64 bf16
    float* s_i      = (float*)(h16 + (long)n * 64); // n
    float* s_j      = s_i + n;                      // n
    int* offs       = (int*)(s_j + n);              // n
    int* counts     = offs + n;                     // n
    int* bcursor    = counts + n;                   // 512
    unsigned* pairs = (unsigned*)(bcursor + 512);   // nb*CAP (aliased as srcl after binB)

    (void)hipMemsetAsync(bcursor, 0, 512 * sizeof(int), stream);

    int blocks_rows = (n + 63) / 64;                // 1563
    int blocks_binA = (n_edges + 8191) / 8192;      // 391
    k_front<<<blocks_binA + blocks_rows, 512, 0, stream>>>(
        A, W, att, h16, s_i, s_j, n, edges, bcursor, pairs, n_edges, nb, blocks_binA);

    k_binB<<<nb, 512, 0, stream>>>(bcursor, pairs, offs, counts, n);

    int blocks_waves = ((long)n * 64 + 255) / 256;  // wave per dst
    k_gather<<<blocks_waves, 256, 0, stream>>>(offs, counts, (const int*)pairs, h16,
                                               s_i, s_j, bias, (float*)d_out, n);
}

// Round 13
// 193.186 us; speedup vs baseline: 1.1697x; 1.0237x over previous
//
#include <hip/hip_runtime.h>
#include <hip/hip_bf16.h>

#define NEG_SLOPE 0.2f
#define BSHIFT 8                 // 256 dsts per bucket
#define BSIZE  (1 << BSHIFT)
#define CAP    9216              // pairs capacity per bucket (mean 8192, +11 sigma)
#define NBMAX  400               // max buckets (n<=102400)
#define SRC_MASK 0x1FFFF         // 17 bits for src id (n < 131072)

typedef float v2f __attribute__((ext_vector_type(2)));

__device__ __forceinline__ float lrelu(float x) { return fmaxf(x, NEG_SLOPE * x); }
__device__ __forceinline__ float bf2f(unsigned short u) {
    return __uint_as_float((unsigned)u << 16);
}
__device__ __forceinline__ unsigned short f2bf(float f) {
    unsigned u = __float_as_uint(f);
    return (unsigned short)((u + 0x7fffu + ((u >> 16) & 1u)) >> 16);  // RNE
}

// Fused front: blocks [0, nba) run binA; blocks [nba, ...) run the GEMM.
// (round-12 version, verified)
__global__ __launch_bounds__(512, 8) void k_front(
    const float* __restrict__ A, const float* __restrict__ W,
    const float* __restrict__ att,
    unsigned short* __restrict__ h16, float* __restrict__ s_i, float* __restrict__ s_j, int n,
    const int* __restrict__ edges, int* __restrict__ bcursor,
    unsigned* __restrict__ pairs, int n_edges, int nb, int nba)
{
    __shared__ union {
        struct { float At[64 * 68]; float Wl[64 * 68]; } g;              // 34816 B
        struct { int hist[512]; int st[512]; int cur[512];
                 int gbase[512]; unsigned lp[8192]; } b;                 // 40960 B
    } sh;
    const int t = threadIdx.x;

    if ((int)blockIdx.x < nba) {
        // ---------------- binA body ----------------
        int* hist = sh.b.hist; int* st = sh.b.st; int* cur = sh.b.cur;
        int* gbase = sh.b.gbase; unsigned* lp = sh.b.lp;
        int* wsum = gbase + 504;         // alias: gbase[504..511] unused (nb<=400)
        const int w = t >> 6, lane = t & 63;
        const long base = (long)blockIdx.x * 8192;

        int er[16];
#pragma unroll
        for (int k = 0; k < 16; ++k) {
            long e = base + k * 512 + t;
            int d = -1;
            if (e < n_edges) {
                d = edges[e];
                if (d == (int)(e >> 5)) d = -1;   // drop self-loops
            }
            er[k] = d;
        }

        hist[t] = 0;
        __syncthreads();
#pragma unroll
        for (int k = 0; k < 16; ++k)
            if (er[k] >= 0) atomicAdd(&hist[er[k] >> BSHIFT], 1);
        __syncthreads();

        int hv = hist[t];
        int inc = hv;
#pragma unroll
        for (int off = 1; off < 64; off <<= 1) {
            int u = __shfl_up(inc, off, 64);
            if (lane >= off) inc += u;
        }
        if (lane == 63) wsum[w] = inc;
        __syncthreads();
        {
            int wb_ = 0;
            for (int i = 0; i < w; ++i) wb_ += wsum[i];   // wave-uniform
            int s0 = inc - hv + wb_;                       // exclusive prefix
            st[t] = s0;
            cur[t] = s0;
            if (t < NBMAX) gbase[t] = 0;                   // guard: keep wsum alias intact
        }
        __syncthreads();                                   // wsum reads done before reserve
        if (t < nb && hist[t] > 0) gbase[t] = atomicAdd(&bcursor[t], hist[t]);
        __syncthreads();

#pragma unroll
        for (int k = 0; k < 16; ++k) {
            int d = er[k];
            if (d >= 0) {
                int b = d >> BSHIFT;
                int slot = atomicAdd(&cur[b], 1);
                long e = base + k * 512 + t;
                lp[slot] = ((unsigned)(d & (BSIZE - 1)) << 17) | (unsigned)(e >> 5);
            }
        }
        __syncthreads();

        for (int b = w; b < nb; b += 8) {
            int cnt = hist[b];
            int gb  = gbase[b];
            int cw  = cnt;
            if (gb + cw > CAP) cw = CAP - gb;   // overflow guard
            long gdst = (long)b * CAP + gb;
            int sb = st[b];
            for (int s = lane; s < cw; s += 64)
                pairs[gdst + s] = lp[sb + s];
        }
    } else {
        // ---------------- gemm body (512-thread variant) ----------------
        float* At = sh.g.At; float* Wl = sh.g.Wl;
        const int lane = t & 63;
        const int tx = t & 15, ty = t >> 4;       // 32 x 16 threads
        const int r0 = ty * 2, c0 = tx * 4;       // 2x4 register tile
        const long row0 = (long)(blockIdx.x - nba) * 64;

        {
            int r = t & 63;
            int kb = (t >> 6) * 4;                // 0,4,...,28
            long gr = row0 + r; if (gr >= n) gr = n - 1;
            const float4* Ar = (const float4*)(A + gr * 64);
#pragma unroll
            for (int p = 0; p < 2; ++p) {
                int k0 = p * 32 + kb;
                float4 a = Ar[k0 >> 2];
                At[(k0 + 0) * 68 + r] = a.x;
                At[(k0 + 1) * 68 + r] = a.y;
                At[(k0 + 2) * 68 + r] = a.z;
                At[(k0 + 3) * 68 + r] = a.w;
            }
            int rr = t >> 4;                      // 0..31
#pragma unroll
            for (int p = 0; p < 2; ++p) {
                int k = rr + p * 32;
                *(float4*)&Wl[k * 68 + c0] = *(const float4*)(W + k * 64 + c0);
            }
        }
        __syncthreads();

        float acc[2][4] = {};
#pragma unroll 4
        for (int k = 0; k < 64; ++k) {
            float2 a = *(const float2*)&At[k * 68 + r0];
            float4 w4 = *(const float4*)&Wl[k * 68 + c0];
            acc[0][0] = fmaf(a.x, w4.x, acc[0][0]);
            acc[0][1] = fmaf(a.x, w4.y, acc[0][1]);
            acc[0][2] = fmaf(a.x, w4.z, acc[0][2]);
            acc[0][3] = fmaf(a.x, w4.w, acc[0][3]);
            acc[1][0] = fmaf(a.y, w4.x, acc[1][0]);
            acc[1][1] = fmaf(a.y, w4.y, acc[1][1]);
            acc[1][2] = fmaf(a.y, w4.z, acc[1][2]);
            acc[1][3] = fmaf(a.y, w4.w, acc[1][3]);
        }

        const int rowlim = (int)(((long)n - row0) < 64 ? (n - row0) : 64);

#pragma unroll
        for (int i = 0; i < 2; ++i) {
            int r = r0 + i;
            if (r < rowlim) {
                uint2 uv;
                uv.x = (unsigned)f2bf(acc[i][0]) | ((unsigned)f2bf(acc[i][1]) << 16);
                uv.y = (unsigned)f2bf(acc[i][2]) | ((unsigned)f2bf(acc[i][3]) << 16);
                *(uint2*)(h16 + (row0 + r) * 64 + c0) = uv;
            }
        }

        float4 avi = *(const float4*)(att + c0);
        float4 avj = *(const float4*)(att + 64 + c0);
#pragma unroll
        for (int i = 0; i < 2; ++i) {
            float pi = acc[i][0] * avi.x;
            pi = fmaf(acc[i][1], avi.y, pi);
            pi = fmaf(acc[i][2], avi.z, pi);
            pi = fmaf(acc[i][3], avi.w, pi);
            float pj = acc[i][0] * avj.x;
            pj = fmaf(acc[i][1], avj.y, pj);
            pj = fmaf(acc[i][2], avj.z, pj);
            pj = fmaf(acc[i][3], avj.w, pj);
#pragma unroll
            for (int o = 1; o <= 8; o <<= 1) {
                pi += __shfl_xor(pi, o, 64);
                pj += __shfl_xor(pj, o, 64);
            }
            int r = r0 + i;
            if ((lane & 15) == 0 && r < rowlim) {
                s_i[row0 + r] = pi;
                s_j[row0 + r] = pj;
            }
        }
    }
}

// Bin step B: counting sort per bucket, wave-shfl scan (round-10 version).
__global__ __launch_bounds__(512) void k_binB(
    const int* __restrict__ bcursor, unsigned* __restrict__ pairs,
    int* __restrict__ offs, int* __restrict__ counts, int n)
{
    __shared__ unsigned pl[CAP];         // 36 KB
    __shared__ unsigned srt[CAP];        // 36 KB
    __shared__ int hist[BSIZE];
    __shared__ int cur[BSIZE];
    __shared__ int wsum[4];
    int b = blockIdx.x, t = threadIdx.x;
    const int w = t >> 6, lane = t & 63;
    int cnt = bcursor[b];
    if (cnt > CAP) cnt = CAP;
    long wb = (long)b * CAP;

    for (int s = t; s < cnt; s += 512) pl[s] = pairs[wb + s];
    if (t < BSIZE) hist[t] = 0;
    __syncthreads();
    for (int s = t; s < cnt; s += 512) atomicAdd(&hist[pl[s] >> 17], 1);
    __syncthreads();

    int hv = (t < BSIZE) ? hist[t] : 0;
    int inc = hv;
#pragma unroll
    for (int off = 1; off < 64; off <<= 1) {
        int u = __shfl_up(inc, off, 64);
        if (lane >= off) inc += u;
    }
    if (t < BSIZE && lane == 63) wsum[w] = inc;
    __syncthreads();
    if (t < BSIZE) {
        int wb_ = 0;
        for (int i = 0; i < w; ++i) wb_ += wsum[i];
        int start = inc - hv + wb_;
        int dg = (b << BSHIFT) + t;
        if (dg < n) {
            offs[dg]   = (int)(wb + start);
            counts[dg] = hv;
        }
        cur[t] = start;
    }
    __syncthreads();

    for (int s = t; s < cnt; s += 512) {
        unsigned pk = pl[s];
        int pos = atomicAdd(&cur[pk >> 17], 1);
        srt[pos] = pk & SRC_MASK;
    }
    __syncthreads();

    for (int s = t; s < cnt; s += 512)
        ((int*)pairs)[wb + s] = (int)srt[s];
}

// Gather: TWO dsts per wave (32 lanes each; 4 groups x 8 lanes per half).
// Per-dst FIXED overhead (acc-reduce shfl tree, den/sq reduces, epilogue
// VALU, offs/counts/hd loads) was ~60% of the old kernel's issue budget at
// deg~32; sharing it across 2 dsts halves that term. Per-edge inner cost is
// instruction-identical (same fma/shfl/load per edge). Paired dsts run to
// max(deg0,deg1); inert lanes (w=0) keep extras numerically inert.
__global__ __launch_bounds__(256) void k_gather(
    const int* __restrict__ offs, const int* __restrict__ counts,
    const int* __restrict__ srcl, const unsigned short* __restrict__ h16,
    const float* __restrict__ s_i, const float* __restrict__ s_j,
    const float* __restrict__ bias, float* __restrict__ out, int n)
{
    int gw = (blockIdx.x * 256 + threadIdx.x) >> 6;
    int lane = threadIdx.x & 63;
    long d0 = (long)gw << 1;
    if (d0 >= n) return;
    const int half = lane >> 5;                    // which dst of the pair
    const int hl   = lane & 31;
    const int d    = (int)d0 + half;
    const bool valid = (d < n);
    const int dc   = valid ? d : n - 1;            // clamped (loads safe, store guarded)

    const int off = offs[dc];
    const int deg = valid ? counts[dc] : 0;
    const float si = s_i[dc];
    const float es = valid ? __expf(lrelu(si + s_j[dc])) : 0.f;

    const int g2 = hl >> 3;                        // group 0..3 within half
    const int li = hl & 7;                         // dims [li*8, li*8+8)
    const char* hb = (const char*)h16 + (li << 4); // +16B per lane-in-group

    // epilogue loads issued early
    uint4 hd = *(const uint4*)(hb + ((long)dc << 7));
    const float4* pb = (const float4*)(bias + (li << 3));
    float4 b0 = pb[0], b1 = pb[1];

    int degmax = max(deg, __shfl_xor(deg, 32, 64));   // pair-common bound

    v2f acc2[4];
#pragma unroll
    for (int i = 0; i < 4; ++i) acc2[i] = (v2f)0.f;
    float denp = 0.f;

    for (int base = 0; base < degmax; base += 32) {
        int t = base + hl;
        int soff = 0; float w = 0.f;
        if (t < deg) {
            int s = srcl[off + t];
            soff = s << 7;                         // byte offset of row s
            w = __expf(lrelu(si + s_j[s]));
        }
        denp += w;
        int cnt = min(32, degmax - base);
        // 8 edges per half per step: 4 segment-shfl + 2 dwordx4 loads
        for (int j = 0; j < cnt; j += 8) {
            int i0 = j + g2, i1 = j + 4 + g2;      // <=31 always (j<=24)
            float w0 = __shfl(w, i0, 32);
            int   o0 = __shfl(soff, i0, 32);
            float w1 = __shfl(w, i1, 32);
            int   o1 = __shfl(soff, i1, 32);
            uint4 ha = *(const uint4*)(hb + o0);
            uint4 hc = *(const uint4*)(hb + o1);
            v2f w0v = {w0, w0};
            v2f w1v = {w1, w1};
            v2f p;
            p = (v2f){__uint_as_float(ha.x << 16), __uint_as_float(ha.x & 0xffff0000u)};
            acc2[0] += p * w0v;
            p = (v2f){__uint_as_float(ha.y << 16), __uint_as_float(ha.y & 0xffff0000u)};
            acc2[1] += p * w0v;
            p = (v2f){__uint_as_float(ha.z << 16), __uint_as_float(ha.z & 0xffff0000u)};
            acc2[2] += p * w0v;
            p = (v2f){__uint_as_float(ha.w << 16), __uint_as_float(ha.w & 0xffff0000u)};
            acc2[3] += p * w0v;
            p = (v2f){__uint_as_float(hc.x << 16), __uint_as_float(hc.x & 0xffff0000u)};
            acc2[0] += p * w1v;
            p = (v2f){__uint_as_float(hc.y << 16), __uint_as_float(hc.y & 0xffff0000u)};
            acc2[1] += p * w1v;
            p = (v2f){__uint_as_float(hc.z << 16), __uint_as_float(hc.z & 0xffff0000u)};
            acc2[2] += p * w1v;
            p = (v2f){__uint_as_float(hc.w << 16), __uint_as_float(hc.w & 0xffff0000u)};
            acc2[3] += p * w1v;
        }
    }

    float acc[8];
    acc[0] = acc2[0].x; acc[1] = acc2[0].y;
    acc[2] = acc2[1].x; acc[3] = acc2[1].y;
    acc[4] = acc2[2].x; acc[5] = acc2[2].y;
    acc[6] = acc2[3].x; acc[7] = acc2[3].y;

    // reduce group partials within each half: group bits are lane bits 3,4
#pragma unroll
    for (int o = 8; o <= 16; o <<= 1) {
#pragma unroll
        for (int i = 0; i < 8; ++i)
            acc[i] += __shfl_xor(acc[i], o, 64);   // stays within 32-lane half
    }
    // den partials within each half (xor <= 16 stays in half)
#pragma unroll
    for (int o = 1; o <= 16; o <<= 1) denp += __shfl_xor(denp, o, 64);

    // self loop + epilogue (per half; hd/bias already in registers)
    float den = denp + es + 1e-16f;
    float rden = 1.f / den;

    float v[8];
    v[0] = fmaf(__uint_as_float(hd.x << 16),         es, acc[0]) * rden + b0.x;
    v[1] = fmaf(__uint_as_float(hd.x & 0xffff0000u), es, acc[1]) * rden + b0.y;
    v[2] = fmaf(__uint_as_float(hd.y << 16),         es, acc[2]) * rden + b0.z;
    v[3] = fmaf(__uint_as_float(hd.y & 0xffff0000u), es, acc[3]) * rden + b0.w;
    v[4] = fmaf(__uint_as_float(hd.z << 16),         es, acc[4]) * rden + b1.x;
    v[5] = fmaf(__uint_as_float(hd.z & 0xffff0000u), es, acc[5]) * rden + b1.y;
    v[6] = fmaf(__uint_as_float(hd.w << 16),         es, acc[6]) * rden + b1.z;
    v[7] = fmaf(__uint_as_float(hd.w & 0xffff0000u), es, acc[7]) * rden + b1.w;

    float sq = 0.f;
#pragma unroll
    for (int i = 0; i < 8; ++i) sq = fmaf(v[i], v[i], sq);
#pragma unroll
    for (int o = 1; o <= 4; o <<= 1) sq += __shfl_xor(sq, o, 64);  // within li bits
    float rn = 1.f / fmaxf(sqrtf(sq), 1e-12f);

    if (valid && g2 < 2) {   // groups 0/1 of each half write dims once each
        float4 ov;
        if (g2 == 0) ov = make_float4(v[0] * rn, v[1] * rn, v[2] * rn, v[3] * rn);
        else         ov = make_float4(v[4] * rn, v[5] * rn, v[6] * rn, v[7] * rn);
        *(float4*)(out + ((long)d << 6) + (li << 3) + (g2 << 2)) = ov;
    }
}

extern "C" void kernel_launch(void* const* d_in, const int* in_sizes, int n_in,
                              void* d_out, int out_size, void* d_ws, size_t ws_size,
                              hipStream_t stream)
{
    const float* A    = (const float*)d_in[0]; // all_embed (n,64) f32
    const float* W    = (const float*)d_in[1]; // (64,64) f32
    const float* att  = (const float*)d_in[2]; // (128,) f32
    const float* bias = (const float*)d_in[3]; // (64,) f32
    const int* edges  = (const int*)d_in[7];   // (n,32) int32

    int n = in_sizes[0] / 64;          // 100000
    int n_edges = in_sizes[7];         // n * 32
    int nb = (n + BSIZE - 1) >> BSHIFT; // 391 buckets

    // workspace layout
    unsigned short* h16 = (unsigned short*)d_ws;    // n*64 bf16
    float* s_i      = (float*)(h16 + (long)n * 64); // n
    float* s_j      = s_i + n;                      // n
    int* offs       = (int*)(s_j + n);              // n
    int* counts     = offs + n;                     // n
    int* bcursor    = counts + n;                   // 512
    unsigned* pairs = (unsigned*)(bcursor + 512);   // nb*CAP (aliased as srcl after binB)

    (void)hipMemsetAsync(bcursor, 0, 512 * sizeof(int), stream);

    int blocks_rows = (n + 63) / 64;                // 1563
    int blocks_binA = (n_edges + 8191) / 8192;      // 391
    k_front<<<blocks_binA + blocks_rows, 512, 0, stream>>>(
        A, W, att, h16, s_i, s_j, n, edges, bcursor, pairs, n_edges, nb, blocks_binA);

    k_binB<<<nb, 512, 0, stream>>>(bcursor, pairs, offs, counts, n);

    int nw = (n + 1) / 2;                           // waves (2 dsts each)
    int blocks_waves = (nw + 3) / 4;                // 4 waves per 256-thr block
    k_gather<<<blocks_waves, 256, 0, stream>>>(offs, counts, (const int*)pairs, h16,
                                               s_i, s_j, bias, (float*)d_out, n);
}